// Round 1
// baseline (576.053 us; speedup 1.0000x reference)
//
#include <hip/hip_runtime.h>

typedef __attribute__((ext_vector_type(8))) short  s16x8;   // 8 x bf16 (MFMA A/B frag)
typedef __attribute__((ext_vector_type(4))) short  s16x4;
typedef __attribute__((ext_vector_type(4))) float  f32x4;   // MFMA C/D frag

#define T_LEN 50000
#define S_LEN 168
#define W_IN  336
#define O_OUT 48
#define N_ROWS (T_LEN - W_IN - O_OUT + 1)   // 49617
#define N_PAD  49664                        // 776 * 64
#define NBLK   (N_PAD / 64)                 // 776

__device__ inline short f2bf(float f) {
    union { float f; unsigned u; } v; v.f = f;
    unsigned u = v.u;
    unsigned r = u + 0x7fffu + ((u >> 16) & 1u);   // RNE
    return (short)(r >> 16);
}

// ---------------- pre-convert W1 -> W1T bf16 [336][352], W2 -> W2T bf16 [48][360] ----------
__global__ void k_preconvert(const float* __restrict__ W1, const float* __restrict__ W2,
                             short* __restrict__ W1T, short* __restrict__ W2T) {
    int idx = blockIdx.x * 256 + threadIdx.x;
    const int n1 = 336 * 352;
    const int tot = n1 + 48 * 360;
    if (idx >= tot) return;
    if (idx < n1) {
        int j = idx / 352, k = idx % 352;
        W1T[idx] = (k < 336) ? f2bf(W1[k * 336 + j]) : (short)0;
    } else {
        int i2 = idx - n1;
        int o = i2 / 360, k = i2 % 360;
        W2T[i2] = (k < 336) ? f2bf(W2[k * 48 + o]) : (short)0;
    }
}

// ---------------- sequential scan: chunk-64 Kogge-Stone on linear level recurrence ---------
__global__ void k_scan(const float* __restrict__ x, const float* __restrict__ level_sc,
                       const float* __restrict__ seas_sc, const float* __restrict__ init_seas,
                       float* __restrict__ levels, float* __restrict__ seas_full) {
    __shared__ float ring[256];
    int lane = threadIdx.x;   // 64 threads, 1 wave
    float a = 1.f / (1.f + expf(-level_sc[0]));
    float g = 1.f / (1.f + expf(-seas_sc[0]));
    float om  = 1.f - a;
    float omg = 1.f - g;

    for (int t = lane; t <= S_LEN; t += 64) {
        float s = expf(init_seas[t < S_LEN ? t : 0]);
        ring[t & 255] = s;
        seas_full[t]  = s;
    }
    float level_prev = x[0] / expf(init_seas[0]);
    if (lane == 0) levels[0] = level_prev;
    __syncthreads();

    float pl   = powf(om, (float)(lane + 1));   // om^(lane+1)
    float om1 = om, om2 = om1 * om1, om4 = om2 * om2,
          om8 = om4 * om4, om16 = om8 * om8, om32 = om16 * om16;

    for (int base = 1; base < T_LEN; base += 64) {
        int i = base + lane;
        bool active = (i < T_LEN);
        float xi = active ? x[i] : 0.f;
        float seas_i = ring[i & 255];
        if (!active) seas_i = 1.f;
        float c = a * xi / seas_i;

        float Q = c, qn;
        qn = __shfl_up(Q, 1, 64);  if (lane >= 1)  Q = fmaf(om1,  qn, Q);
        qn = __shfl_up(Q, 2, 64);  if (lane >= 2)  Q = fmaf(om2,  qn, Q);
        qn = __shfl_up(Q, 4, 64);  if (lane >= 4)  Q = fmaf(om4,  qn, Q);
        qn = __shfl_up(Q, 8, 64);  if (lane >= 8)  Q = fmaf(om8,  qn, Q);
        qn = __shfl_up(Q, 16, 64); if (lane >= 16) Q = fmaf(om16, qn, Q);
        qn = __shfl_up(Q, 32, 64); if (lane >= 32) Q = fmaf(om32, qn, Q);

        float lvl = fmaf(pl, level_prev, Q);
        if (active) {
            levels[i] = lvl;
            float w = fmaf(omg, seas_i, g * xi / lvl);
            seas_full[S_LEN + i] = w;
            ring[(S_LEN + i) & 255] = w;
        }
        level_prev = __shfl(lvl, 63, 64);
        __syncthreads();
    }
}

// ---------------- logs ---------------------------------------------------------------------
__global__ void k_logs(const float* __restrict__ x, const float* __restrict__ levels,
                       const float* __restrict__ seas_full,
                       float* __restrict__ logx, float* __restrict__ llev,
                       float* __restrict__ logseas) {
    int t = blockIdx.x * 256 + threadIdx.x;
    if (t < T_LEN) { logx[t] = logf(x[t]); llev[t] = logf(levels[t]); }
    if (t < S_LEN + T_LEN) logseas[t] = logf(seas_full[t]);
}

// ---------------- level_var_loss (deterministic two-pass) ----------------------------------
__global__ void k_loss_partial(const float* __restrict__ llev, float* __restrict__ partials) {
    __shared__ float sm[256];
    const int M = T_LEN - 2;            // 49998
    const int per = (M + 63) / 64;      // 782
    int j0 = blockIdx.x * per;
    int j1 = j0 + per; if (j1 > M) j1 = M;
    float s = 0.f;
    for (int j = j0 + threadIdx.x; j < j1; j += 256) {
        float d = llev[j + 2] - 2.f * llev[j + 1] + llev[j];
        s += d * d;
    }
    sm[threadIdx.x] = s; __syncthreads();
    for (int off = 128; off > 0; off >>= 1) {
        if ((int)threadIdx.x < off) sm[threadIdx.x] += sm[threadIdx.x + off];
        __syncthreads();
    }
    if (threadIdx.x == 0) partials[blockIdx.x] = sm[0];
}

__global__ void k_loss_final(const float* __restrict__ partials, const int* __restrict__ lvp,
                             float* __restrict__ out_loss) {
    int lane = threadIdx.x; // 64
    float s = partials[lane];
    for (int off = 32; off > 0; off >>= 1) s += __shfl_down(s, off, 64);
    if (lane == 0) out_loss[0] = s / (float)(T_LEN - 2) * (float)lvp[0];
}

// ---------------- labels -------------------------------------------------------------------
__global__ void k_labels(const float* __restrict__ logx, const float* __restrict__ llev,
                         const float* __restrict__ logseas, float* __restrict__ labels) {
    int idx = blockIdx.x * 256 + threadIdx.x;
    if (idx >= N_ROWS * O_OUT) return;
    int n = idx / O_OUT, o = idx - n * O_OUT;
    int tt = n + W_IN + o;
    labels[idx] = logx[tt] - llev[n + W_IN] - logseas[tt];
}

// ---------------- GEMM1: h = tanh(inp @ W1 + b1), inp built on the fly ----------------------
__global__ __launch_bounds__(256) void k_gemm1(
        const float* __restrict__ noise, const float* __restrict__ logx,
        const float* __restrict__ logseas, const float* __restrict__ llev,
        const short* __restrict__ W1T, const float* __restrict__ b1,
        short* __restrict__ h) {
    __shared__ short Alds[64][40];    // [row][k] bf16, stride 40 (80B, 16B-aligned rows)
    __shared__ short Blds[336][40];   // [col j][k] bf16 (pre-transposed)
    int t = threadIdx.x;
    int wave = t >> 6, lane = t & 63;
    long n0 = (long)blockIdx.x * 64;

    f32x4 acc[21];
#pragma unroll
    for (int ct = 0; ct < 21; ++ct) acc[ct] = (f32x4){0.f, 0.f, 0.f, 0.f};

    int arow = t >> 2;            // 0..63
    int akq  = (t & 3) * 8;       // 0,8,16,24
    long an = n0 + arow;
    float lv = llev[an + W_IN];
    const float* nrow = noise + an * W_IN;
    bool nvalid = (an < N_ROWS);

    for (int ks = 0; ks < 11; ++ks) {
        int k0 = ks * 32;
        // stage A: each thread computes 8 consecutive inp values, packs bf16, one b128 store
        {
            s16x8 pv;
#pragma unroll
            for (int j = 0; j < 8; ++j) {
                int kk = k0 + akq + j;
                float v = 0.f;
                if (kk < W_IN) {
                    v = logx[an + kk] - lv - logseas[an + kk];
                    if (nvalid) v += nrow[kk];
                }
                pv[j] = f2bf(v);
            }
            *(s16x8*)&Alds[arow][akq] = pv;
        }
        // stage B: copy W1T[j][k0..k0+31] (already bf16, zero-padded)
#pragma unroll
        for (int it = 0; it < 11; ++it) {
            int q = t + it * 256;
            if (q < 2688) {
                int j = q >> 3, k4 = (q & 7) * 4;
                *(s16x4*)&Blds[j][k4] = *(const s16x4*)&W1T[j * 352 + k0 + k4];
            }
        }
        __syncthreads();
        s16x8 af = *(s16x8*)&Alds[wave * 16 + (lane & 15)][(lane >> 4) * 8];
#pragma unroll
        for (int ct = 0; ct < 21; ++ct) {
            s16x8 bf = *(s16x8*)&Blds[ct * 16 + (lane & 15)][(lane >> 4) * 8];
            acc[ct] = __builtin_amdgcn_mfma_f32_16x16x32_bf16(af, bf, acc[ct], 0, 0, 0);
        }
        __syncthreads();
    }
    // epilogue: + b1, tanh, store bf16 h (all N_PAD rows; pad rows hold tanh(b1), harmless)
    long rbase = n0 + wave * 16 + ((lane >> 4) << 2);
    int cl = lane & 15;
#pragma unroll
    for (int ct = 0; ct < 21; ++ct) {
        float bb = b1[ct * 16 + cl];
#pragma unroll
        for (int r = 0; r < 4; ++r) {
            float v = tanhf(acc[ct][r] + bb);
            h[(rbase + r) * W_IN + ct * 16 + cl] = f2bf(v);
        }
    }
}

// ---------------- GEMM2: out = h @ W2 + b2 ---------------------------------------------------
__global__ __launch_bounds__(256) void k_gemm2(
        const short* __restrict__ h, const short* __restrict__ W2T,
        const float* __restrict__ b2, float* __restrict__ out) {
    __shared__ short Blds[48 * 360];   // whole W2T bf16
    int t = threadIdx.x, wave = t >> 6, lane = t & 63;
#pragma unroll
    for (int it = 0; it < 17; ++it) {
        int q = t + it * 256;
        if (q < 4320) *(s16x4*)&Blds[q * 4] = *(const s16x4*)&W2T[q * 4];
    }
    __syncthreads();
    long n0 = (long)blockIdx.x * 64;
    f32x4 acc[3];
#pragma unroll
    for (int ct = 0; ct < 3; ++ct) acc[ct] = (f32x4){0.f, 0.f, 0.f, 0.f};
    long arow = n0 + wave * 16 + (lane & 15);
    int kgrp = (lane >> 4) * 8;
#pragma unroll
    for (int ks = 0; ks < 11; ++ks) {
        int kA = ks * 32 + kgrp;
        s16x8 af = (s16x8){0,0,0,0,0,0,0,0};
        if (kA < W_IN) af = *(const s16x8*)&h[arow * W_IN + kA];
#pragma unroll
        for (int ct = 0; ct < 3; ++ct) {
            s16x8 bf = *(s16x8*)&Blds[(ct * 16 + (lane & 15)) * 360 + ks * 32 + kgrp];
            acc[ct] = __builtin_amdgcn_mfma_f32_16x16x32_bf16(af, bf, acc[ct], 0, 0, 0);
        }
    }
    long rbase = n0 + wave * 16 + ((lane >> 4) << 2);
    int cl = lane & 15;
#pragma unroll
    for (int ct = 0; ct < 3; ++ct) {
        float bb = b2[ct * 16 + cl];
#pragma unroll
        for (int r = 0; r < 4; ++r) {
            long row = rbase + r;
            if (row < N_ROWS) out[row * O_OUT + ct * 16 + cl] = acc[ct][r] + bb;
        }
    }
}

extern "C" void kernel_launch(void* const* d_in, const int* in_sizes, int n_in,
                              void* d_out, int out_size, void* d_ws, size_t ws_size,
                              hipStream_t stream) {
    const float* x         = (const float*)d_in[0];
    const float* noise     = (const float*)d_in[1];
    const float* level_sc  = (const float*)d_in[2];
    const float* seas_sc   = (const float*)d_in[3];
    const float* init_seas = (const float*)d_in[4];
    const float* W1        = (const float*)d_in[5];
    const float* b1        = (const float*)d_in[6];
    const float* W2        = (const float*)d_in[7];
    const float* b2        = (const float*)d_in[8];
    const int*   lvp       = (const int*)d_in[11];

    float* out    = (float*)d_out;
    float* labels = out + (long)N_ROWS * O_OUT;
    float* loss   = labels + (long)N_ROWS * O_OUT;

    // ws layout (float offsets, 16B-aligned blocks)
    float* wsf       = (float*)d_ws;
    float* levels    = wsf;               // 50000 (reserve 50048)
    float* seas_full = wsf + 50048;       // 50168 (reserve 50176)
    float* logx      = wsf + 100224;      // 50000 (reserve 50048)
    float* llev      = wsf + 150272;      // 50000 (reserve 50048)
    float* logseas   = wsf + 200320;      // 50168 (reserve 50176)
    float* partials  = wsf + 250496;      // 64    (reserve 256)
    short* W1T       = (short*)(wsf + 250752);          // 336*352 bf16
    short* W2T       = W1T + 336 * 352;                 // 48*360 bf16
    short* h         = W2T + 48 * 360;                  // N_PAD*336 bf16 (~33.4 MB)

    k_preconvert<<<530, 256, 0, stream>>>(W1, W2, W1T, W2T);
    k_scan<<<1, 64, 0, stream>>>(x, level_sc, seas_sc, init_seas, levels, seas_full);
    k_logs<<<196, 256, 0, stream>>>(x, levels, seas_full, logx, llev, logseas);
    k_loss_partial<<<64, 256, 0, stream>>>(llev, partials);
    k_loss_final<<<1, 64, 0, stream>>>(partials, lvp, loss);
    k_labels<<<(N_ROWS * O_OUT + 255) / 256, 256, 0, stream>>>(logx, llev, logseas, labels);
    k_gemm1<<<NBLK, 256, 0, stream>>>(noise, logx, logseas, llev, W1T, b1, h);
    k_gemm2<<<NBLK, 256, 0, stream>>>(h, W2T, b2, out);
}

// Round 2
// 276.413 us; speedup vs baseline: 2.0840x; 2.0840x over previous
//
#include <hip/hip_runtime.h>

typedef __attribute__((ext_vector_type(8))) short  s16x8;   // 8 x bf16 (MFMA A/B frag)
typedef __attribute__((ext_vector_type(4))) short  s16x4;
typedef __attribute__((ext_vector_type(4))) float  f32x4;   // MFMA C/D frag

#define T_LEN 50000
#define S_LEN 168
#define W_IN  336
#define O_OUT 48
#define N_ROWS (T_LEN - W_IN - O_OUT + 1)   // 49617
#define N_PAD  49664                        // 776 * 64
#define NBLK   (N_PAD / 64)                 // 776

__device__ inline short f2bf(float f) {
    union { float f; unsigned u; } v; v.f = f;
    unsigned u = v.u;
    unsigned r = u + 0x7fffu + ((u >> 16) & 1u);   // RNE
    return (short)(r >> 16);
}

__device__ inline float readlane_f(float v, int l) {
    return __int_as_float(__builtin_amdgcn_readlane(__float_as_int(v), l));
}

// ---------------- pre-convert W1 -> W1T bf16 [336][352], W2 -> W2T bf16 [48][360] ----------
__global__ void k_preconvert(const float* __restrict__ W1, const float* __restrict__ W2,
                             short* __restrict__ W1T, short* __restrict__ W2T) {
    int idx = blockIdx.x * 256 + threadIdx.x;
    const int n1 = 336 * 352;
    const int tot = n1 + 48 * 360;
    if (idx >= tot) return;
    if (idx < n1) {
        int j = idx / 352, k = idx % 352;
        W1T[idx] = (k < 336) ? f2bf(W1[k * 336 + j]) : (short)0;
    } else {
        int i2 = idx - n1;
        int o = i2 / 360, k = i2 % 360;
        W2T[i2] = (k < 336) ? f2bf(W2[k * 48 + o]) : (short)0;
    }
}

// ---------------- scan: pipelined chunk-64, DPP weighted Kogge-Stone, rcp ring -------------
// Level recurrence: level_i = c_i + om*level_{i-1}, c_i = a*x_i/seas_i.
// seas_i = seas_full[i]; for i>=169 that is w_{i-168} (written >= ~1.6 chunks earlier),
// so chunk k+1's staging (c + Q-scan) is independent of chunk k's propagation.
#define DPP_STEP(q_, CTRL, OMW) { \
    int t_ = __builtin_amdgcn_update_dpp(0, __float_as_int(q_), (CTRL), 0xf, 0xf, true); \
    q_ = fmaf((OMW), __int_as_float(t_), q_); }

__global__ void k_scan(const float* __restrict__ x, const float* __restrict__ level_sc,
                       const float* __restrict__ seas_sc, const float* __restrict__ init_seas,
                       float* __restrict__ levels, float* __restrict__ seas_full) {
    __shared__ float ringbuf[512];   // [0..255]=w(seas), [256..511]=1/w
    int lane = threadIdx.x;          // 64 threads, 1 wave
    float a = 1.f / (1.f + expf(-level_sc[0]));
    float g = 1.f / (1.f + expf(-seas_sc[0]));
    float om = 1.f - a, omg = 1.f - g;

    // init ring with seas_full[0..168] (s0[0..167], s0[0])
    for (int t = lane; t < 256; t += 64) {
        float s = 1.f;
        if (t <= S_LEN) {
            s = expf(init_seas[t < S_LEN ? t : 0]);
            seas_full[t] = s;
        }
        ringbuf[t] = s;
        ringbuf[t + 256] = 1.f / s;
    }
    float lpv = x[0] / expf(init_seas[0]);   // level_prev (uniform)
    if (lane == 0) levels[0] = lpv;
    __syncthreads();

    float om1 = om, om2 = om1 * om1, om4 = om2 * om2, om8 = om4 * om4, om16 = om8 * om8;
    float pl   = powf(om, (float)(lane + 1));          // om^(lane+1)
    float fpre = powf(om, (float)((lane & 15) + 1));   // om^((lane&15)+1)
    bool isr1 = (lane >> 4) == 1, isr2 = (lane >> 4) == 2, isr3 = (lane >> 4) == 3;

#define STAGE(OUTQ, OUTS, IB, XV) { \
        int ridx_ = ((IB) + lane) & 255; \
        float s_  = ringbuf[ridx_]; \
        float rs_ = ringbuf[ridx_ + 256]; \
        float q_ = a * (XV) * rs_; \
        DPP_STEP(q_, 0x111, om1); \
        DPP_STEP(q_, 0x112, om2); \
        DPP_STEP(q_, 0x114, om4); \
        DPP_STEP(q_, 0x118, om8); \
        float e0_ = readlane_f(q_, 15); \
        float e1_ = readlane_f(q_, 31); \
        float e2_ = readlane_f(q_, 47); \
        float t2_ = fmaf(om16, e0_, e1_); \
        float t3_ = fmaf(om16, t2_, e2_); \
        float pre_ = isr1 ? e0_ : (isr2 ? t2_ : (isr3 ? t3_ : 0.f)); \
        OUTQ = fmaf(fpre, pre_, q_); \
        OUTS = s_; }

    // prologue: x pipeline 3 deep, stage chunk 0
    float x0 = x[1 + lane];      // chunk 0
    float xA = x[65 + lane];     // chunk 1
    float xB = x[129 + lane];    // chunk 2
    float Qk, sk, xk;
    STAGE(Qk, sk, 1, x0);
    xk = x0;

    int ib = 1;
    for (int k = 0; k < 780; ++k, ib += 64) {
        // prefetch x for chunk k+3 (clamped; clamped lanes only feed dead Q lanes of tail)
        int pidx = ib + 192 + lane;
        pidx = pidx > (T_LEN - 1) ? (T_LEN - 1) : pidx;
        float xnew = x[pidx];
        // stage chunk k+1 (independent of chunk k's level)
        float Qn, sn;
        STAGE(Qn, sn, ib + 64, xA);
        // propagate chunk k
        float lvl = fmaf(pl, lpv, Qk);
        lpv = readlane_f(lvl, 63);
        levels[ib + lane] = lvl;
        float rl = __builtin_amdgcn_rcpf(lvl);
        float w_ = fmaf(omg, sk, (g * xk) * rl);
        float rw_ = __builtin_amdgcn_rcpf(w_);
        int widx = (ib + S_LEN + lane) & 255;
        ringbuf[widx] = w_;
        ringbuf[widx + 256] = rw_;
        seas_full[S_LEN + ib + lane] = w_;
        // shift pipeline
        Qk = Qn; sk = sn; xk = xA; xA = xB; xB = xnew;
    }
    // epilogue: ib == 49921. Stage chunk 781 (partial), propagate 780, propagate 781 masked.
    float Qn, sn;
    STAGE(Qn, sn, 49985, xA);
    {   // propagate chunk 780 (steps 49921..49984, full)
        float lvl = fmaf(pl, lpv, Qk);
        lpv = readlane_f(lvl, 63);
        levels[49921 + lane] = lvl;
        float rl = __builtin_amdgcn_rcpf(lvl);
        float w_ = fmaf(omg, sk, (g * xk) * rl);
        seas_full[S_LEN + 49921 + lane] = w_;
    }
    {   // propagate chunk 781 (steps 49985..49999, lanes 0..14)
        float lvl = fmaf(pl, lpv, Qn);
        if (49985 + lane < T_LEN) {
            levels[49985 + lane] = lvl;
            float rl = __builtin_amdgcn_rcpf(lvl);
            float w_ = fmaf(omg, sn, (g * xA) * rl);
            seas_full[S_LEN + 49985 + lane] = w_;
        }
    }
#undef STAGE
}

// ---------------- logs ---------------------------------------------------------------------
__global__ void k_logs(const float* __restrict__ x, const float* __restrict__ levels,
                       const float* __restrict__ seas_full,
                       float* __restrict__ logx, float* __restrict__ llev,
                       float* __restrict__ logseas) {
    int t = blockIdx.x * 256 + threadIdx.x;
    if (t < T_LEN) { logx[t] = logf(x[t]); llev[t] = logf(levels[t]); }
    if (t < S_LEN + T_LEN) logseas[t] = logf(seas_full[t]);
}

// ---------------- level_var_loss (deterministic two-pass) ----------------------------------
__global__ void k_loss_partial(const float* __restrict__ llev, float* __restrict__ partials) {
    __shared__ float sm[256];
    const int M = T_LEN - 2;            // 49998
    const int per = (M + 63) / 64;      // 782
    int j0 = blockIdx.x * per;
    int j1 = j0 + per; if (j1 > M) j1 = M;
    float s = 0.f;
    for (int j = j0 + threadIdx.x; j < j1; j += 256) {
        float d = llev[j + 2] - 2.f * llev[j + 1] + llev[j];
        s += d * d;
    }
    sm[threadIdx.x] = s; __syncthreads();
    for (int off = 128; off > 0; off >>= 1) {
        if ((int)threadIdx.x < off) sm[threadIdx.x] += sm[threadIdx.x + off];
        __syncthreads();
    }
    if (threadIdx.x == 0) partials[blockIdx.x] = sm[0];
}

__global__ void k_loss_final(const float* __restrict__ partials, const int* __restrict__ lvp,
                             float* __restrict__ out_loss) {
    int lane = threadIdx.x; // 64
    float s = partials[lane];
    for (int off = 32; off > 0; off >>= 1) s += __shfl_down(s, off, 64);
    if (lane == 0) out_loss[0] = s / (float)(T_LEN - 2) * (float)lvp[0];
}

// ---------------- labels -------------------------------------------------------------------
__global__ void k_labels(const float* __restrict__ logx, const float* __restrict__ llev,
                         const float* __restrict__ logseas, float* __restrict__ labels) {
    int idx = blockIdx.x * 256 + threadIdx.x;
    if (idx >= N_ROWS * O_OUT) return;
    int n = idx / O_OUT, o = idx - n * O_OUT;
    int tt = n + W_IN + o;
    labels[idx] = logx[tt] - llev[n + W_IN] - logseas[tt];
}

// ---------------- GEMM1: h = tanh(inp @ W1 + b1), inp built on the fly ----------------------
__global__ __launch_bounds__(256) void k_gemm1(
        const float* __restrict__ noise, const float* __restrict__ logx,
        const float* __restrict__ logseas, const float* __restrict__ llev,
        const short* __restrict__ W1T, const float* __restrict__ b1,
        short* __restrict__ h) {
    __shared__ short Alds[64][40];    // [row][k] bf16, stride 40 (80B, 16B-aligned rows)
    __shared__ short Blds[336][40];   // [col j][k] bf16 (pre-transposed)
    int t = threadIdx.x;
    int wave = t >> 6, lane = t & 63;
    long n0 = (long)blockIdx.x * 64;

    f32x4 acc[21];
#pragma unroll
    for (int ct = 0; ct < 21; ++ct) acc[ct] = (f32x4){0.f, 0.f, 0.f, 0.f};

    int arow = t >> 2;            // 0..63
    int akq  = (t & 3) * 8;       // 0,8,16,24
    long an = n0 + arow;
    float lv = llev[an + W_IN];
    const float* nrow = noise + an * W_IN;
    bool nvalid = (an < N_ROWS);

    for (int ks = 0; ks < 11; ++ks) {
        int k0 = ks * 32;
        // stage A: each thread computes 8 consecutive inp values, packs bf16, one b128 store
        {
            s16x8 pv;
#pragma unroll
            for (int j = 0; j < 8; ++j) {
                int kk = k0 + akq + j;
                float v = 0.f;
                if (kk < W_IN) {
                    v = logx[an + kk] - lv - logseas[an + kk];
                    if (nvalid) v += nrow[kk];
                }
                pv[j] = f2bf(v);
            }
            *(s16x8*)&Alds[arow][akq] = pv;
        }
        // stage B: copy W1T[j][k0..k0+31] (already bf16, zero-padded)
#pragma unroll
        for (int it = 0; it < 11; ++it) {
            int q = t + it * 256;
            if (q < 2688) {
                int j = q >> 3, k4 = (q & 7) * 4;
                *(s16x4*)&Blds[j][k4] = *(const s16x4*)&W1T[j * 352 + k0 + k4];
            }
        }
        __syncthreads();
        s16x8 af = *(s16x8*)&Alds[wave * 16 + (lane & 15)][(lane >> 4) * 8];
#pragma unroll
        for (int ct = 0; ct < 21; ++ct) {
            s16x8 bf = *(s16x8*)&Blds[ct * 16 + (lane & 15)][(lane >> 4) * 8];
            acc[ct] = __builtin_amdgcn_mfma_f32_16x16x32_bf16(af, bf, acc[ct], 0, 0, 0);
        }
        __syncthreads();
    }
    // epilogue: + b1, tanh, store bf16 h (all N_PAD rows; pad rows hold tanh(b1), harmless)
    long rbase = n0 + wave * 16 + ((lane >> 4) << 2);
    int cl = lane & 15;
#pragma unroll
    for (int ct = 0; ct < 21; ++ct) {
        float bb = b1[ct * 16 + cl];
#pragma unroll
        for (int r = 0; r < 4; ++r) {
            float v = tanhf(acc[ct][r] + bb);
            h[(rbase + r) * W_IN + ct * 16 + cl] = f2bf(v);
        }
    }
}

// ---------------- GEMM2: out = h @ W2 + b2 ---------------------------------------------------
__global__ __launch_bounds__(256) void k_gemm2(
        const short* __restrict__ h, const short* __restrict__ W2T,
        const float* __restrict__ b2, float* __restrict__ out) {
    __shared__ short Blds[48 * 360];   // whole W2T bf16
    int t = threadIdx.x, wave = t >> 6, lane = t & 63;
#pragma unroll
    for (int it = 0; it < 17; ++it) {
        int q = t + it * 256;
        if (q < 4320) *(s16x4*)&Blds[q * 4] = *(const s16x4*)&W2T[q * 4];
    }
    __syncthreads();
    long n0 = (long)blockIdx.x * 64;
    f32x4 acc[3];
#pragma unroll
    for (int ct = 0; ct < 3; ++ct) acc[ct] = (f32x4){0.f, 0.f, 0.f, 0.f};
    long arow = n0 + wave * 16 + (lane & 15);
    int kgrp = (lane >> 4) * 8;
#pragma unroll
    for (int ks = 0; ks < 11; ++ks) {
        int kA = ks * 32 + kgrp;
        s16x8 af = (s16x8){0,0,0,0,0,0,0,0};
        if (kA < W_IN) af = *(const s16x8*)&h[arow * W_IN + kA];
#pragma unroll
        for (int ct = 0; ct < 3; ++ct) {
            s16x8 bf = *(s16x8*)&Blds[(ct * 16 + (lane & 15)) * 360 + ks * 32 + kgrp];
            acc[ct] = __builtin_amdgcn_mfma_f32_16x16x32_bf16(af, bf, acc[ct], 0, 0, 0);
        }
    }
    long rbase = n0 + wave * 16 + ((lane >> 4) << 2);
    int cl = lane & 15;
#pragma unroll
    for (int ct = 0; ct < 3; ++ct) {
        float bb = b2[ct * 16 + cl];
#pragma unroll
        for (int r = 0; r < 4; ++r) {
            long row = rbase + r;
            if (row < N_ROWS) out[row * O_OUT + ct * 16 + cl] = acc[ct][r] + bb;
        }
    }
}

extern "C" void kernel_launch(void* const* d_in, const int* in_sizes, int n_in,
                              void* d_out, int out_size, void* d_ws, size_t ws_size,
                              hipStream_t stream) {
    const float* x         = (const float*)d_in[0];
    const float* noise     = (const float*)d_in[1];
    const float* level_sc  = (const float*)d_in[2];
    const float* seas_sc   = (const float*)d_in[3];
    const float* init_seas = (const float*)d_in[4];
    const float* W1        = (const float*)d_in[5];
    const float* b1        = (const float*)d_in[6];
    const float* W2        = (const float*)d_in[7];
    const float* b2        = (const float*)d_in[8];
    const int*   lvp       = (const int*)d_in[11];

    float* out    = (float*)d_out;
    float* labels = out + (long)N_ROWS * O_OUT;
    float* loss   = labels + (long)N_ROWS * O_OUT;

    // ws layout (float offsets, 16B-aligned blocks)
    float* wsf       = (float*)d_ws;
    float* levels    = wsf;               // 50000 (reserve 50048)
    float* seas_full = wsf + 50048;       // 50168 (reserve 50176)
    float* logx      = wsf + 100224;      // 50000 (reserve 50048)
    float* llev      = wsf + 150272;      // 50000 (reserve 50048)
    float* logseas   = wsf + 200320;      // 50168 (reserve 50176)
    float* partials  = wsf + 250496;      // 64    (reserve 256)
    short* W1T       = (short*)(wsf + 250752);          // 336*352 bf16
    short* W2T       = W1T + 336 * 352;                 // 48*360 bf16
    short* h         = W2T + 48 * 360;                  // N_PAD*336 bf16 (~33.4 MB)

    k_preconvert<<<530, 256, 0, stream>>>(W1, W2, W1T, W2T);
    k_scan<<<1, 64, 0, stream>>>(x, level_sc, seas_sc, init_seas, levels, seas_full);
    k_logs<<<196, 256, 0, stream>>>(x, levels, seas_full, logx, llev, logseas);
    k_loss_partial<<<64, 256, 0, stream>>>(llev, partials);
    k_loss_final<<<1, 64, 0, stream>>>(partials, lvp, loss);
    k_labels<<<(N_ROWS * O_OUT + 255) / 256, 256, 0, stream>>>(logx, llev, logseas, labels);
    k_gemm1<<<NBLK, 256, 0, stream>>>(noise, logx, logseas, llev, W1T, b1, h);
    k_gemm2<<<NBLK, 256, 0, stream>>>(h, W2T, b2, out);
}

// Round 3
// 184.749 us; speedup vs baseline: 3.1180x; 1.4962x over previous
//
#include <hip/hip_runtime.h>

typedef __attribute__((ext_vector_type(8))) short  s16x8;   // 8 x bf16 (MFMA A/B frag)
typedef __attribute__((ext_vector_type(4))) short  s16x4;
typedef __attribute__((ext_vector_type(4))) float  f32x4;   // MFMA C/D frag
typedef __attribute__((ext_vector_type(2))) float  f32x2;

#define T_LEN 50000
#define S_LEN 168
#define W_IN  336
#define O_OUT 48
#define N_ROWS (T_LEN - W_IN - O_OUT + 1)   // 49617
#define N_PAD  49664                        // 776 * 64
#define NBLK   (N_PAD / 64)                 // 776

__device__ inline short f2bf(float f) {
    union { float f; unsigned u; } v; v.f = f;
    unsigned u = v.u;
    unsigned r = u + 0x7fffu + ((u >> 16) & 1u);   // RNE
    return (short)(r >> 16);
}

__device__ inline float readlane_f(float v, int l) {
    return __int_as_float(__builtin_amdgcn_readlane(__float_as_int(v), l));
}

__device__ inline float fast_tanh(float v) {
    float e = __expf(2.f * v);
    return 1.f - 2.f * __builtin_amdgcn_rcpf(e + 1.f);
}

// ---------------- pre-convert W1 -> W1T bf16 [336][352], W2 -> W2T bf16 [48][360] ----------
__global__ void k_preconvert(const float* __restrict__ W1, const float* __restrict__ W2,
                             short* __restrict__ W1T, short* __restrict__ W2T) {
    int idx = blockIdx.x * 256 + threadIdx.x;
    const int n1 = 336 * 352;
    const int tot = n1 + 48 * 360;
    if (idx >= tot) return;
    if (idx < n1) {
        int j = idx / 352, k = idx % 352;
        W1T[idx] = (k < 336) ? f2bf(W1[k * 336 + j]) : (short)0;
    } else {
        int i2 = idx - n1;
        int o = i2 / 360, k = i2 % 360;
        W2T[i2] = (k < 336) ? f2bf(W2[k * 48 + o]) : (short)0;
    }
}

// ---------------- scan: 16-deep x prefetch, 1-iter-early ring reads, DPP scan --------------
#define DPP_STEP(q_, CTRL, OMW) { \
    int t_ = __builtin_amdgcn_update_dpp(0, __float_as_int(q_), (CTRL), 0xf, 0xf, true); \
    q_ = fmaf((OMW), __int_as_float(t_), q_); }

__global__ void k_scan(const float* __restrict__ x, const float* __restrict__ level_sc,
                       const float* __restrict__ seas_sc, const float* __restrict__ init_seas,
                       float* __restrict__ levels, float* __restrict__ seas_full) {
    __shared__ __align__(16) float ring2[512];   // [i*2]=w, [i*2+1]=1/w
    int lane = threadIdx.x;          // 64 threads, 1 wave
    float a = 1.f / (1.f + expf(-level_sc[0]));
    float g = 1.f / (1.f + expf(-seas_sc[0]));
    float om = 1.f - a, omg = 1.f - g;

    for (int t = lane; t < 256; t += 64) {
        float s = 1.f;
        if (t <= S_LEN) { s = expf(init_seas[t < S_LEN ? t : 0]); seas_full[t] = s; }
        ring2[t * 2] = s;
        ring2[t * 2 + 1] = 1.f / s;
    }
    float lpv = x[0] / expf(init_seas[0]);
    if (lane == 0) levels[0] = lpv;
    __syncthreads();

    float om1 = om, om2v = om1 * om1, om4 = om2v * om2v, om8 = om4 * om4, om16 = om8 * om8;
    float pl   = powf(om, (float)(lane + 1));
    float fpre = powf(om, (float)((lane & 15) + 1));
    bool isr1 = (lane >> 4) == 1, isr2 = (lane >> 4) == 2, isr3 = (lane >> 4) == 3;

#define SCAN(QOUT, XV, RSV) { \
    float q_ = a * (XV) * (RSV); \
    DPP_STEP(q_, 0x111, om1); \
    DPP_STEP(q_, 0x112, om2v); \
    DPP_STEP(q_, 0x114, om4); \
    DPP_STEP(q_, 0x118, om8); \
    float e0_ = readlane_f(q_, 15); \
    float e1_ = readlane_f(q_, 31); \
    float e2_ = readlane_f(q_, 47); \
    float t2_ = fmaf(om16, e0_, e1_); \
    float t3_ = fmaf(om16, t2_, e2_); \
    float pre_ = isr1 ? e0_ : (isr2 ? t2_ : (isr3 ? t3_ : 0.f)); \
    QOUT = fmaf(fpre, pre_, q_); }

    // x prefetch registers: slot i holds chunk i initially (chunk c covers steps 1+64c..64+64c)
#define XLOAD(I) float xr##I = x[1 + 64 * I + lane];
    XLOAD(0) XLOAD(1) XLOAD(2) XLOAD(3) XLOAD(4) XLOAD(5) XLOAD(6) XLOAD(7)
    XLOAD(8) XLOAD(9) XLOAD(10) XLOAD(11) XLOAD(12) XLOAD(13) XLOAD(14) XLOAD(15)
#undef XLOAD

    // prologue: scan chunk 0; issue ring reads chunk 1
    f32x2 rc0 = *(f32x2*)&ring2[(1 + lane) * 2];
    float Qcur; SCAN(Qcur, xr0, rc0[1]);
    float scur = rc0[0];
    f32x2 rp = *(f32x2*)&ring2[(65 + lane) * 2];
    float s_p = rp[0], rs_p = rp[1];
    int ib = 1;

    // iter k: propagate chunk k (x=xr[k%16]); issue ring reads chunk k+2;
    //         scan chunk k+1 (x=xr[(k+1)%16], rs_p from iter k-1); prefetch chunk k+16.
#define BODY(R, RN) { \
    float lvl = fmaf(pl, lpv, Qcur); \
    lpv = readlane_f(lvl, 63); \
    levels[ib + lane] = lvl; \
    float rl = __builtin_amdgcn_rcpf(lvl); \
    float w_ = fmaf(omg, scur, (g * xr##R) * rl); \
    float rw_ = __builtin_amdgcn_rcpf(w_); \
    int widx = (ib + S_LEN + lane) & 255; \
    *(f32x2*)&ring2[widx * 2] = (f32x2){w_, rw_}; \
    seas_full[S_LEN + ib + lane] = w_; \
    int ridx = (ib + 128 + lane) & 255; \
    f32x2 rr = *(f32x2*)&ring2[ridx * 2]; \
    float Qn_; SCAN(Qn_, xr##RN, rs_p); \
    int pidx = ib + 1024 + lane; pidx = pidx > (T_LEN - 1) ? (T_LEN - 1) : pidx; \
    xr##R = x[pidx]; \
    Qcur = Qn_; scur = s_p; s_p = rr[0]; rs_p = rr[1]; \
    ib += 64; }

    for (int kb = 0; kb < 48; ++kb) {   // 48*16 = 768 iters
        BODY(0,1)  BODY(1,2)  BODY(2,3)  BODY(3,4)
        BODY(4,5)  BODY(5,6)  BODY(6,7)  BODY(7,8)
        BODY(8,9)  BODY(9,10) BODY(10,11) BODY(11,12)
        BODY(12,13) BODY(13,14) BODY(14,15) BODY(15,0)
    }
    // 12 tail iters: k = 768..779 (slots 0..11); chunks 780,781 live in slots 12,13
    BODY(0,1)  BODY(1,2)  BODY(2,3)  BODY(3,4)
    BODY(4,5)  BODY(5,6)  BODY(6,7)  BODY(7,8)
    BODY(8,9)  BODY(9,10) BODY(10,11) BODY(11,12)
#undef BODY

    {   // propagate chunk 780 (steps 49921..49984, full)
        float lvl = fmaf(pl, lpv, Qcur);
        lpv = readlane_f(lvl, 63);
        levels[49921 + lane] = lvl;
        float rl = __builtin_amdgcn_rcpf(lvl);
        float w_ = fmaf(omg, scur, (g * xr12) * rl);
        seas_full[S_LEN + 49921 + lane] = w_;
    }
    {   // chunk 781 (steps 49985..49999, lanes 0..14)
        float Qn_; SCAN(Qn_, xr13, rs_p);
        float lvl = fmaf(pl, lpv, Qn_);
        if (lane < 15) {
            levels[49985 + lane] = lvl;
            float rl = __builtin_amdgcn_rcpf(lvl);
            float w_ = fmaf(omg, s_p, (g * xr13) * rl);
            seas_full[S_LEN + 49985 + lane] = w_;
        }
    }
#undef SCAN
}

// ---------------- logs: F[t] = log(x)-log(seas), llev = log(levels) ------------------------
__global__ void k_logs(const float* __restrict__ x, const float* __restrict__ levels,
                       const float* __restrict__ seas_full,
                       float* __restrict__ F, float* __restrict__ llev) {
    int t = blockIdx.x * 256 + threadIdx.x;
    if (t < T_LEN) {
        F[t]    = __logf(x[t]) - __logf(seas_full[t]);
        llev[t] = __logf(levels[t]);
    }
}

// ---------------- level_var_loss (deterministic two-pass) ----------------------------------
__global__ void k_loss_partial(const float* __restrict__ llev, float* __restrict__ partials) {
    __shared__ float sm[256];
    const int M = T_LEN - 2;            // 49998
    const int per = (M + 63) / 64;      // 782
    int j0 = blockIdx.x * per;
    int j1 = j0 + per; if (j1 > M) j1 = M;
    float s = 0.f;
    for (int j = j0 + threadIdx.x; j < j1; j += 256) {
        float d = llev[j + 2] - 2.f * llev[j + 1] + llev[j];
        s += d * d;
    }
    sm[threadIdx.x] = s; __syncthreads();
    for (int off = 128; off > 0; off >>= 1) {
        if ((int)threadIdx.x < off) sm[threadIdx.x] += sm[threadIdx.x + off];
        __syncthreads();
    }
    if (threadIdx.x == 0) partials[blockIdx.x] = sm[0];
}

__global__ void k_loss_final(const float* __restrict__ partials, const int* __restrict__ lvp,
                             float* __restrict__ out_loss) {
    int lane = threadIdx.x; // 64
    float s = partials[lane];
    for (int off = 32; off > 0; off >>= 1) s += __shfl_down(s, off, 64);
    if (lane == 0) out_loss[0] = s / (float)(T_LEN - 2) * (float)lvp[0];
}

// ---------------- fused GEMM: h = tanh(inp@W1+b1) in LDS; out = h@W2+b2; labels ------------
__global__ __launch_bounds__(256) void k_gemm(
        const float* __restrict__ noise, const float* __restrict__ F,
        const float* __restrict__ llev, const short* __restrict__ W1T,
        const float* __restrict__ b1, const short* __restrict__ W2T,
        const float* __restrict__ b2, float* __restrict__ out,
        float* __restrict__ labels) {
    __shared__ __align__(16) short hlds[64][360];   // bf16 h tile, cols 336..351 zeroed
    __shared__ __align__(16) char  uni[34560];      // phase1: Alds+Blds; phase2: W2lds
    short (*Alds)[40] = (short(*)[40])uni;          // 64 x 40  (5120 B)
    short (*Blds)[40] = (short(*)[40])(uni + 5120); // 336 x 40 (26880 B)
    short* W2lds = (short*)uni;                     // 48 x 360 (34560 B)

    int t = threadIdx.x;
    int wave = t >> 6, lane = t & 63;
    long n0 = (long)blockIdx.x * 64;

    f32x4 acc[21];
#pragma unroll
    for (int ct = 0; ct < 21; ++ct) acc[ct] = (f32x4){0.f, 0.f, 0.f, 0.f};

    int arow = t >> 2;            // 0..63
    int akq  = (t & 3) * 8;       // 0,8,16,24
    long an = n0 + arow;
    float lv = llev[an + W_IN];
    const float* nrow = noise + an * (long)W_IN;
    bool nvalid = (an < N_ROWS);

    for (int ks = 0; ks < 11; ++ks) {
        int k0 = ks * 32;
        // stage A: inp[arow][k0+akq .. +7] = F[an+kk] - lv + noise
        {
            f32x4 nz0 = (f32x4){0,0,0,0}, nz1 = (f32x4){0,0,0,0};
            if (nvalid && (k0 + akq) < W_IN) {
                nz0 = *(const f32x4*)&nrow[k0 + akq];
                nz1 = *(const f32x4*)&nrow[k0 + akq + 4];
            }
            s16x8 pv;
#pragma unroll
            for (int j = 0; j < 8; ++j) {
                int kk = k0 + akq + j;
                float v = 0.f;
                if (kk < W_IN)
                    v = F[an + kk] - lv + (j < 4 ? nz0[j] : nz1[j - 4]);
                pv[j] = f2bf(v);
            }
            *(s16x8*)&Alds[arow][akq] = pv;
        }
        // stage B: W1T[j][k0..k0+31]
#pragma unroll
        for (int it = 0; it < 11; ++it) {
            int q = t + it * 256;
            if (q < 2688) {
                int j = q >> 3, k4 = (q & 7) * 4;
                *(s16x4*)&Blds[j][k4] = *(const s16x4*)&W1T[j * 352 + k0 + k4];
            }
        }
        __syncthreads();
        s16x8 af = *(s16x8*)&Alds[wave * 16 + (lane & 15)][(lane >> 4) * 8];
#pragma unroll
        for (int ct = 0; ct < 21; ++ct) {
            s16x8 bf = *(s16x8*)&Blds[ct * 16 + (lane & 15)][(lane >> 4) * 8];
            acc[ct] = __builtin_amdgcn_mfma_f32_16x16x32_bf16(af, bf, acc[ct], 0, 0, 0);
        }
        __syncthreads();
    }

    // zero-pad hlds cols 336..351 (cols 352..359 never read)
    *(s16x4*)&hlds[t >> 2][336 + (t & 3) * 4] = (s16x4){0, 0, 0, 0};

    // epilogue 1: bias + fast tanh -> hlds (bf16)
    int rb_local = wave * 16 + ((lane >> 4) << 2);
    int cl = lane & 15;
#pragma unroll
    for (int ct = 0; ct < 21; ++ct) {
        float bb = b1[ct * 16 + cl];
#pragma unroll
        for (int r = 0; r < 4; ++r) {
            float v = fast_tanh(acc[ct][r] + bb);
            hlds[rb_local + r][ct * 16 + cl] = f2bf(v);
        }
    }
    __syncthreads();

    // stage W2lds (uni region reused)
#pragma unroll
    for (int it = 0; it < 17; ++it) {
        int q = t + it * 256;
        if (q < 4320) *(s16x4*)&W2lds[q * 4] = *(const s16x4*)&W2T[q * 4];
    }
    __syncthreads();

    // gemm2: out-tile = h @ W2
    f32x4 acc2[3];
#pragma unroll
    for (int ct = 0; ct < 3; ++ct) acc2[ct] = (f32x4){0.f, 0.f, 0.f, 0.f};
    int kgrp = (lane >> 4) * 8;
#pragma unroll
    for (int ks = 0; ks < 11; ++ks) {
        s16x8 af2 = *(s16x8*)&hlds[wave * 16 + (lane & 15)][ks * 32 + kgrp];
#pragma unroll
        for (int ct = 0; ct < 3; ++ct) {
            s16x8 bf2 = *(s16x8*)&W2lds[(ct * 16 + (lane & 15)) * 360 + ks * 32 + kgrp];
            acc2[ct] = __builtin_amdgcn_mfma_f32_16x16x32_bf16(af2, bf2, acc2[ct], 0, 0, 0);
        }
    }

    // epilogue 2: out + labels
    long rbase = n0 + rb_local;
#pragma unroll
    for (int ct = 0; ct < 3; ++ct) {
        float bb = b2[ct * 16 + cl];
#pragma unroll
        for (int r = 0; r < 4; ++r) {
            long row = rbase + r;
            if (row < N_ROWS) {
                int col = ct * 16 + cl;
                out[row * O_OUT + col] = acc2[ct][r] + bb;
                long tt = row + W_IN + col;
                labels[row * O_OUT + col] = F[tt] - llev[row + W_IN];
            }
        }
    }
}

extern "C" void kernel_launch(void* const* d_in, const int* in_sizes, int n_in,
                              void* d_out, int out_size, void* d_ws, size_t ws_size,
                              hipStream_t stream) {
    const float* x         = (const float*)d_in[0];
    const float* noise     = (const float*)d_in[1];
    const float* level_sc  = (const float*)d_in[2];
    const float* seas_sc   = (const float*)d_in[3];
    const float* init_seas = (const float*)d_in[4];
    const float* W1        = (const float*)d_in[5];
    const float* b1        = (const float*)d_in[6];
    const float* W2        = (const float*)d_in[7];
    const float* b2        = (const float*)d_in[8];
    const int*   lvp       = (const int*)d_in[11];

    float* out    = (float*)d_out;
    float* labels = out + (long)N_ROWS * O_OUT;
    float* loss   = labels + (long)N_ROWS * O_OUT;

    float* wsf       = (float*)d_ws;
    float* levels    = wsf;               // 50000 (reserve 50048)
    float* seas_full = wsf + 50048;       // 50168 (reserve 50176)
    float* F         = wsf + 100224;      // 50000 (reserve 50048)
    float* llev      = wsf + 150272;      // 50000 (reserve 50048)
    float* partials  = wsf + 200320;      // 64    (reserve 256)
    short* W1T       = (short*)(wsf + 200576);   // 336*352 bf16
    short* W2T       = W1T + 336 * 352;          // 48*360 bf16

    k_preconvert<<<530, 256, 0, stream>>>(W1, W2, W1T, W2T);
    k_scan<<<1, 64, 0, stream>>>(x, level_sc, seas_sc, init_seas, levels, seas_full);
    k_logs<<<196, 256, 0, stream>>>(x, levels, seas_full, F, llev);
    k_loss_partial<<<64, 256, 0, stream>>>(llev, partials);
    k_loss_final<<<1, 64, 0, stream>>>(partials, lvp, loss);
    k_gemm<<<NBLK, 256, 0, stream>>>(noise, F, llev, W1T, b1, W2T, b2, out, labels);
}

// Round 5
// 168.374 us; speedup vs baseline: 3.4213x; 1.0973x over previous
//
#include <hip/hip_runtime.h>

typedef __attribute__((ext_vector_type(8))) short  s16x8;   // 8 x bf16
typedef __attribute__((ext_vector_type(4))) short  s16x4;
typedef __attribute__((ext_vector_type(4))) float  f32x4;

#define T_LEN 50000
#define S_LEN 168
#define W_IN  336
#define O_OUT 48
#define N_ROWS (T_LEN - W_IN - O_OUT + 1)   // 49617
#define N_PAD  49664                        // 776 * 64
#define NBLK   (N_PAD / 64)                 // 776

__device__ inline short f2bf(float f) {
    union { float f; unsigned u; } v; v.f = f;
    unsigned u = v.u;
    unsigned r = u + 0x7fffu + ((u >> 16) & 1u);   // RNE
    return (short)(r >> 16);
}

__device__ inline float readlane_f(float v, int l) {
    return __int_as_float(__builtin_amdgcn_readlane(__float_as_int(v), l));
}

__device__ inline float fast_tanh(float v) {
    float e = __expf(2.f * v);
    return 1.f - 2.f * __builtin_amdgcn_rcpf(e + 1.f);
}

// ---------------- pre-convert W1 -> W1T bf16 [352][352] (zero-padded), W2 -> W2T [48][360] --
__global__ void k_preconvert(const float* __restrict__ W1, const float* __restrict__ W2,
                             short* __restrict__ W1T, short* __restrict__ W2T) {
    int idx = blockIdx.x * 256 + threadIdx.x;
    const int n1 = 352 * 352;
    const int tot = n1 + 48 * 360;
    if (idx >= tot) return;
    if (idx < n1) {
        int j = idx / 352, k = idx % 352;
        W1T[idx] = (j < 336 && k < 336) ? f2bf(W1[k * 336 + j]) : (short)0;
    } else {
        int i2 = idx - n1;
        int o = i2 / 360, k = i2 % 360;
        W2T[i2] = (k < 336) ? f2bf(W2[k * 48 + o]) : (short)0;
    }
}

// ---------------- scan: chunk-64, ping-pong LDS regs, w-only ring, DPP scan ----------------
#define DPP_STEP(q_, CTRL, OMW) { \
    int t_ = __builtin_amdgcn_update_dpp(0, __float_as_int(q_), (CTRL), 0xf, 0xf, true); \
    q_ = fmaf((OMW), __int_as_float(t_), q_); }

__global__ void k_scan(const float* __restrict__ x, const float* __restrict__ level_sc,
                       const float* __restrict__ seas_sc, const float* __restrict__ init_seas,
                       float* __restrict__ levels, float* __restrict__ seas_full) {
    __shared__ float ring[256];      // ring[s & 255] = seas(s)
    int lane = threadIdx.x;          // 64 threads, 1 wave
    float a = 1.f / (1.f + expf(-level_sc[0]));
    float g = 1.f / (1.f + expf(-seas_sc[0]));
    float om = 1.f - a, omg = 1.f - g;

    for (int t = lane; t < 256; t += 64) {
        float s = 1.f;
        if (t <= S_LEN) { s = expf(init_seas[t < S_LEN ? t : 0]); seas_full[t] = s; }
        ring[t] = s;
    }
    float lpv = x[0] / expf(init_seas[0]);
    if (lane == 0) levels[0] = lpv;
    __syncthreads();

    float om1 = om, om2v = om1 * om1, om4 = om2v * om2v, om8 = om4 * om4, om16 = om8 * om8;
    float pl   = powf(om, (float)(lane + 1));
    float fpre = powf(om, (float)((lane & 15) + 1));
    bool isr1 = (lane >> 4) == 1, isr2 = (lane >> 4) == 2, isr3 = (lane >> 4) == 3;

#define SCAN(QOUT, XV, RSV) { \
    float q_ = a * (XV) * (RSV); \
    DPP_STEP(q_, 0x111, om1); \
    DPP_STEP(q_, 0x112, om2v); \
    DPP_STEP(q_, 0x114, om4); \
    DPP_STEP(q_, 0x118, om8); \
    float e0_ = readlane_f(q_, 15); \
    float e1_ = readlane_f(q_, 31); \
    float e2_ = readlane_f(q_, 47); \
    float t2_ = fmaf(om16, e0_, e1_); \
    float t3_ = fmaf(om16, t2_, e2_); \
    float pre_ = isr1 ? e0_ : (isr2 ? t2_ : (isr3 ? t3_ : 0.f)); \
    QOUT = fmaf(fpre, pre_, q_); }

#define XLOAD(I) float xr##I = x[1 + 64 * I + lane];
    XLOAD(0) XLOAD(1) XLOAD(2) XLOAD(3) XLOAD(4) XLOAD(5) XLOAD(6) XLOAD(7)
    XLOAD(8) XLOAD(9) XLOAD(10) XLOAD(11) XLOAD(12) XLOAD(13) XLOAD(14) XLOAD(15)
#undef XLOAD

    // prologue: seas chunk 0; scan chunk 0; issue read for chunk 1
    float sA0 = ring[1 + lane];
    float Qcur; SCAN(Qcur, xr0, __builtin_amdgcn_rcpf(sA0));
    float sW = sA0;
    float ldsA = ring[65 + lane];   // seas chunk 1 (consumed iter 0)
    float ldsB;
    int ib = 1;

    // iter k: propagate chunk k; ring-write w(k); issue ring-read for chunk k+2 (-> LOUT);
    //         scan chunk k+1 from LIN (read issued last iter); prefetch x chunk k+16.
#define BODY(R, RN, LIN, LOUT) { \
    float lvl = fmaf(pl, lpv, Qcur); \
    lpv = readlane_f(lvl, 63); \
    levels[ib + lane] = lvl; \
    float w_ = fmaf(omg, sW, (g * xr##R) * __builtin_amdgcn_rcpf(lvl)); \
    seas_full[S_LEN + ib + lane] = w_; \
    ring[(ib + S_LEN + lane) & 255] = w_; \
    LOUT = ring[(ib + 128 + lane) & 255]; \
    float rsn_ = __builtin_amdgcn_rcpf(LIN); \
    float Qn_; SCAN(Qn_, xr##RN, rsn_); \
    int pidx = ib + 1024 + lane; pidx = pidx > (T_LEN - 1) ? (T_LEN - 1) : pidx; \
    xr##R = x[pidx]; \
    Qcur = Qn_; sW = LIN; \
    ib += 64; }

    for (int kb = 0; kb < 48; ++kb) {   // 48*16 = 768 iters
        BODY(0,1,  ldsA, ldsB) BODY(1,2,  ldsB, ldsA) BODY(2,3,  ldsA, ldsB) BODY(3,4,  ldsB, ldsA)
        BODY(4,5,  ldsA, ldsB) BODY(5,6,  ldsB, ldsA) BODY(6,7,  ldsA, ldsB) BODY(7,8,  ldsB, ldsA)
        BODY(8,9,  ldsA, ldsB) BODY(9,10, ldsB, ldsA) BODY(10,11,ldsA, ldsB) BODY(11,12,ldsB, ldsA)
        BODY(12,13,ldsA, ldsB) BODY(13,14,ldsB, ldsA) BODY(14,15,ldsA, ldsB) BODY(15,0, ldsB, ldsA)
    }
    // 12 tail iters: k = 768..779
    BODY(0,1,  ldsA, ldsB) BODY(1,2,  ldsB, ldsA) BODY(2,3,  ldsA, ldsB) BODY(3,4,  ldsB, ldsA)
    BODY(4,5,  ldsA, ldsB) BODY(5,6,  ldsB, ldsA) BODY(6,7,  ldsA, ldsB) BODY(7,8,  ldsB, ldsA)
    BODY(8,9,  ldsA, ldsB) BODY(9,10, ldsB, ldsA) BODY(10,11,ldsA, ldsB) BODY(11,12,ldsB, ldsA)
#undef BODY

    {   // propagate chunk 780 (steps 49921..49984; sW = seas(780), Qcur = Q(780))
        float lvl = fmaf(pl, lpv, Qcur);
        lpv = readlane_f(lvl, 63);
        levels[49921 + lane] = lvl;
        float w_ = fmaf(omg, sW, (g * xr12) * __builtin_amdgcn_rcpf(lvl));
        seas_full[S_LEN + 49921 + lane] = w_;
    }
    {   // chunk 781 (steps 49985..49999, lanes 0..14; ldsA = seas(781) pending)
        float rsn_ = __builtin_amdgcn_rcpf(ldsA);
        float Qn_; SCAN(Qn_, xr13, rsn_);
        float lvl = fmaf(pl, lpv, Qn_);
        if (lane < 15) {
            levels[49985 + lane] = lvl;
            float w_ = fmaf(omg, ldsA, (g * xr13) * __builtin_amdgcn_rcpf(lvl));
            seas_full[S_LEN + 49985 + lane] = w_;
        }
    }
#undef SCAN
}

// ---------------- logs + loss partials: F, llev, and per-block sum of d^2 -------------------
__global__ void k_logs(const float* __restrict__ x, const float* __restrict__ levels,
                       const float* __restrict__ seas_full,
                       float* __restrict__ F, float* __restrict__ llev,
                       float* __restrict__ partials) {
    __shared__ float sm[258];
    __shared__ float red[256];
    int tid = threadIdx.x;
    int t = blockIdx.x * 256 + tid;
    float ll = 0.f;
    if (t < T_LEN) {
        F[t]  = __logf(x[t]) - __logf(seas_full[t]);
        ll    = __logf(levels[t]);
        llev[t] = ll;
    }
    sm[tid] = ll;
    if (tid < 2) {
        int te = blockIdx.x * 256 + 256 + tid;
        sm[256 + tid] = (te < T_LEN) ? __logf(levels[te]) : 0.f;
    }
    __syncthreads();
    float s = 0.f;
    if (t < T_LEN - 2) {
        float d = sm[tid + 2] - 2.f * sm[tid + 1] + sm[tid];
        s = d * d;
    }
    red[tid] = s; __syncthreads();
    for (int off = 128; off > 0; off >>= 1) {
        if (tid < off) red[tid] += red[tid + off];
        __syncthreads();
    }
    if (tid == 0) partials[blockIdx.x] = red[0];
}

// ---------------- fused GEMM: reg-built A, swapped MFMA, dbuf Blds, 3 blocks/CU -------------
__global__ __launch_bounds__(256, 3) void k_gemm(
        const float* __restrict__ noise, const float* __restrict__ F,
        const float* __restrict__ llev, const short* __restrict__ W1T,
        const float* __restrict__ b1, const short* __restrict__ W2T,
        const float* __restrict__ b2, const float* __restrict__ partials,
        const int* __restrict__ lvp, float* __restrict__ out,
        float* __restrict__ labels, float* __restrict__ loss) {
    __shared__ __align__(16) short Bb[2][352 * 36];   // 50688 B; phase2: hlds[64][360] aliases
    __shared__ __align__(16) float Flds[448];
    __shared__ __align__(16) float Llds[64];
    __shared__ __align__(16) float b1lds[352];

    int t = threadIdx.x, w = t >> 6, l = t & 63;
    int lm = l & 15, lq = l >> 4;
    long n0 = (long)blockIdx.x * 64;

    // loss final (block 0, wave 3) — independent, no extra barriers
    if (blockIdx.x == 0 && w == 3) {
        float s = partials[l] + partials[l + 64] + partials[l + 128];
        if (l < 4) s += partials[l + 192];
#pragma unroll
        for (int off = 32; off > 0; off >>= 1) s += __shfl_down(s, off, 64);
        if (l == 0) loss[0] = s / (float)(T_LEN - 2) * (float)lvp[0];
    }

    // stage Flds / Llds / b1lds
    if (t < 112)      *(f32x4*)&Flds[t * 4] = *(const f32x4*)&F[n0 + t * 4];
    else if (t < 128) *(f32x4*)&Llds[(t - 112) * 4] = *(const f32x4*)&llev[n0 + W_IN + (t - 112) * 4];
    else if (t < 216) {
        int i4 = (t - 128) * 4;
        f32x4 v = (f32x4){0.f, 0.f, 0.f, 0.f};
        if (i4 < W_IN) v = *(const f32x4*)&b1[i4];
        *(f32x4*)&b1lds[i4] = v;
    }
    // stage Blds buf0 (ks=0)
#pragma unroll
    for (int it = 0; it < 6; ++it) {
        int q = t + it * 256;
        if (q < 1408) {
            int j = q >> 2, kc = q & 3;
            s16x8 v = *(const s16x8*)&W1T[j * 352 + kc * 8];
            *(s16x4*)&Bb[0][j * 36 + kc * 8]     = (s16x4){v[0], v[1], v[2], v[3]};
            *(s16x4*)&Bb[0][j * 36 + kc * 8 + 4] = (s16x4){v[4], v[5], v[6], v[7]};
        }
    }

    int rbase = (w >> 1) * 32;     // sample-row base (2 waves share j-halves)
    int jbase = (w & 1) * 176;     // j base
    long an0 = n0 + rbase + lm, an1 = an0 + 16;
    const long amax = (long)N_ROWS * W_IN - 8;
    long a00 = an0 * W_IN, a10 = an1 * W_IN;

    // prefetch noise ks=0
    long p0 = a00 + lq * 8; if (p0 > amax) p0 = amax;
    long p1 = a10 + lq * 8; if (p1 > amax) p1 = amax;
    f32x4 nc00 = *(const f32x4*)&noise[p0], nc01 = *(const f32x4*)&noise[p0 + 4];
    f32x4 nc10 = *(const f32x4*)&noise[p1], nc11 = *(const f32x4*)&noise[p1 + 4];

    f32x4 acc0[11], acc1[11];
#pragma unroll
    for (int c = 0; c < 11; ++c) { acc0[c] = (f32x4){0,0,0,0}; acc1[c] = (f32x4){0,0,0,0}; }

    __syncthreads();
    float lv0 = Llds[rbase + lm], lv1 = Llds[rbase + 16 + lm];

#pragma unroll
    for (int ks = 0; ks < 11; ++ks) {
        // issue W1 loads for ks+1
        s16x8 wr0, wr1, wr2, wr3, wr4, wr5;
        if (ks < 10) {
            int ko = (ks + 1) * 32;
            wr0 = *(const s16x8*)&W1T[((t       ) >> 2) * 352 + ko + ((t       ) & 3) * 8];
            wr1 = *(const s16x8*)&W1T[((t +  256) >> 2) * 352 + ko + ((t +  256) & 3) * 8];
            wr2 = *(const s16x8*)&W1T[((t +  512) >> 2) * 352 + ko + ((t +  512) & 3) * 8];
            wr3 = *(const s16x8*)&W1T[((t +  768) >> 2) * 352 + ko + ((t +  768) & 3) * 8];
            wr4 = *(const s16x8*)&W1T[((t + 1024) >> 2) * 352 + ko + ((t + 1024) & 3) * 8];
            if (t < 128)
                wr5 = *(const s16x8*)&W1T[((t + 1280) >> 2) * 352 + ko + ((t + 1280) & 3) * 8];
        }
        // issue noise loads for ks+1
        f32x4 nn00, nn01, nn10, nn11;
        if (ks < 10) {
            int kb = (ks + 1) * 32 + lq * 8;
            long q0 = a00 + kb; if (q0 > amax) q0 = amax;
            long q1 = a10 + kb; if (q1 > amax) q1 = amax;
            nn00 = *(const f32x4*)&noise[q0]; nn01 = *(const f32x4*)&noise[q0 + 4];
            nn10 = *(const f32x4*)&noise[q1]; nn11 = *(const f32x4*)&noise[q1 + 4];
        }
        // build inp fragments (B operand of swapped MFMA) in registers
        int fb = rbase + lm + ks * 32 + lq * 8;
        s16x8 bf0, bf1;
#pragma unroll
        for (int j = 0; j < 8; ++j) {
            float nv0 = (j < 4) ? nc00[j] : nc01[j - 4];
            float nv1 = (j < 4) ? nc10[j] : nc11[j - 4];
            bf0[j] = f2bf(Flds[fb + j]      - lv0 + nv0);
            bf1[j] = f2bf(Flds[fb + 16 + j] - lv1 + nv1);
        }
        // MFMA: acc = W1frag * inpfrag  (h comes out transposed)
#pragma unroll
        for (int ct = 0; ct < 11; ++ct) {
            int bo = (jbase + ct * 16 + lm) * 36 + lq * 8;
            s16x4 afl = *(s16x4*)&Bb[ks & 1][bo];
            s16x4 afh = *(s16x4*)&Bb[ks & 1][bo + 4];
            s16x8 af = (s16x8){afl[0], afl[1], afl[2], afl[3], afh[0], afh[1], afh[2], afh[3]};
            acc0[ct] = __builtin_amdgcn_mfma_f32_16x16x32_bf16(af, bf0, acc0[ct], 0, 0, 0);
            acc1[ct] = __builtin_amdgcn_mfma_f32_16x16x32_bf16(af, bf1, acc1[ct], 0, 0, 0);
        }
        // write staged W1 to the other buffer
        if (ks < 10) {
            int nb = (ks + 1) & 1;
#define WST(WR, OFS) { if ((OFS) < 1280 || t < 128) { int q = t + (OFS); int j = q >> 2, kc = q & 3; \
            *(s16x4*)&Bb[nb][j * 36 + kc * 8]     = (s16x4){WR[0], WR[1], WR[2], WR[3]}; \
            *(s16x4*)&Bb[nb][j * 36 + kc * 8 + 4] = (s16x4){WR[4], WR[5], WR[6], WR[7]}; } }
            WST(wr0, 0) WST(wr1, 256) WST(wr2, 512) WST(wr3, 768) WST(wr4, 1024) WST(wr5, 1280)
#undef WST
            nc00 = nn00; nc01 = nn01; nc10 = nn10; nc11 = nn11;
        }
        __syncthreads();
    }

    // epilogue 1: bias + tanh -> hlds (aliases Bb; all Blds reads done past barrier)
    // NOTE: stride MUST be >= 352 (j runs to 351; cols 336..351 are exact zeros via
    // zero-padded W1T rows + zero b1lds -> tanh(0)=0). 360 chosen for bank spread.
    short (*hlds)[360] = (short(*)[360])&Bb[0][0];   // 64*360*2 = 46080 B <= 50688 B
#pragma unroll
    for (int ct = 0; ct < 11; ++ct) {
        f32x4 b1q = *(f32x4*)&b1lds[jbase + ct * 16 + lq * 4];
        s16x4 h0, h1;
#pragma unroll
        for (int r = 0; r < 4; ++r) {
            h0[r] = f2bf(fast_tanh(acc0[ct][r] + b1q[r]));
            h1[r] = f2bf(fast_tanh(acc1[ct][r] + b1q[r]));
        }
        *(s16x4*)&hlds[rbase + lm][jbase + ct * 16 + lq * 4]      = h0;
        *(s16x4*)&hlds[rbase + 16 + lm][jbase + ct * 16 + lq * 4] = h1;
    }
    __syncthreads();

    // gemm2: out-tile = h @ W2 (W2 fragments direct from global; L1/L2-hot)
    f32x4 a2[3];
    a2[0] = (f32x4){0,0,0,0}; a2[1] = (f32x4){0,0,0,0}; a2[2] = (f32x4){0,0,0,0};
#pragma unroll
    for (int ks = 0; ks < 11; ++ks) {
        s16x8 af2 = *(s16x8*)&hlds[w * 16 + lm][ks * 32 + lq * 8];
#pragma unroll
        for (int ct = 0; ct < 3; ++ct) {
            s16x8 bf2 = *(const s16x8*)&W2T[(ct * 16 + lm) * 360 + ks * 32 + lq * 8];
            a2[ct] = __builtin_amdgcn_mfma_f32_16x16x32_bf16(af2, bf2, a2[ct], 0, 0, 0);
        }
    }

    // epilogue 2: out + labels (labels entirely from LDS)
    int rloc = w * 16 + lq * 4;
#pragma unroll
    for (int ct = 0; ct < 3; ++ct) {
        float b2v = b2[ct * 16 + lm];
#pragma unroll
        for (int r = 0; r < 4; ++r) {
            long row = n0 + rloc + r;
            if (row < N_ROWS) {
                int col = ct * 16 + lm;
                out[row * O_OUT + col]    = a2[ct][r] + b2v;
                labels[row * O_OUT + col] = Flds[rloc + r + W_IN + col] - Llds[rloc + r];
            }
        }
    }
}

extern "C" void kernel_launch(void* const* d_in, const int* in_sizes, int n_in,
                              void* d_out, int out_size, void* d_ws, size_t ws_size,
                              hipStream_t stream) {
    const float* x         = (const float*)d_in[0];
    const float* noise     = (const float*)d_in[1];
    const float* level_sc  = (const float*)d_in[2];
    const float* seas_sc   = (const float*)d_in[3];
    const float* init_seas = (const float*)d_in[4];
    const float* W1        = (const float*)d_in[5];
    const float* b1        = (const float*)d_in[6];
    const float* W2        = (const float*)d_in[7];
    const float* b2        = (const float*)d_in[8];
    const int*   lvp       = (const int*)d_in[11];

    float* out    = (float*)d_out;
    float* labels = out + (long)N_ROWS * O_OUT;
    float* loss   = labels + (long)N_ROWS * O_OUT;

    float* wsf       = (float*)d_ws;
    float* levels    = wsf;               // 50000 (reserve 50048)
    float* seas_full = wsf + 50048;       // 50168 (reserve 50176)
    float* F         = wsf + 100224;      // 50000 (reserve 50176; gemm reads to n0+447)
    float* llev      = wsf + 150400;      // 50000 (reserve 50048)
    float* partials  = wsf + 200448;      // 196   (reserve 256)
    short* W1T       = (short*)(wsf + 200704);   // 352*352 bf16 (zero-padded)
    short* W2T       = W1T + 352 * 352;          // 48*360 bf16

    k_preconvert<<<552, 256, 0, stream>>>(W1, W2, W1T, W2T);
    k_scan<<<1, 64, 0, stream>>>(x, level_sc, seas_sc, init_seas, levels, seas_full);
    k_logs<<<196, 256, 0, stream>>>(x, levels, seas_full, F, llev, partials);
    k_gemm<<<NBLK, 256, 0, stream>>>(noise, F, llev, W1T, b1, W2T, b2,
                                     partials, lvp, out, labels, loss);
}